// Round 10
// baseline (716.424 us; speedup 1.0000x reference)
//
#include <hip/hip_runtime.h>

#define FEAT 28            // features per table row
#define LVL  16            // levels
#define NDIR 6             // levels 0..5 are direct (prod(res) <= T)
#define HASH_SIZE 524288u  // T_TABLE; every hashed level has size == 2^19

typedef float    f32x4 __attribute__((ext_vector_type(4)));
typedef _Float16 f16x4 __attribute__((ext_vector_type(4)));
typedef _Float16 f16x8 __attribute__((ext_vector_type(8)));

// ---------------------------------------------------------------------------
// Launch 1: pack hashed rows (offsets[NDIR]..offsets[LVL]) f32 -> fp16
// 64B-padded rows at ws + r*64B. One row per thread, churn grid (R5-proven).
// ---------------------------------------------------------------------------
__global__ __launch_bounds__(256) void pack_hashed_kernel(
    const float* __restrict__ memory, f16x8* __restrict__ wsrow,
    const int* __restrict__ offsets)
{
    const int rBeg = offsets[NDIR];
    const int rEnd = offsets[LVL];
    const int r = rBeg + blockIdx.x * blockDim.x + threadIdx.x;
    if (r >= rEnd) return;
    const float* src = memory + (size_t)r * FEAT;
    f16x8 o[4];
#pragma unroll
    for (int k = 0; k < 32; ++k) {
        const float v = (k < FEAT) ? src[k] : 0.0f;
        o[k >> 3][k & 7] = (_Float16)v;          // RN conversion
    }
    f16x8* dst = wsrow + (size_t)r * 4;
#pragma unroll
    for (int k = 0; k < 4; ++k) dst[k] = o[k];
}

// ---------------------------------------------------------------------------
// Corner indices + weights. EXACT reference numerics: IEEE division, floorf,
// clip, ((wx*wy)*wz) order. Hash-mod via mask is exact: a level is hashed
// iff prod(res) > T, and then its size == T == 2^19.
// ---------------------------------------------------------------------------
__device__ __forceinline__ void point_corners(
    const float* __restrict__ inputs, int n,
    int base, int r0, int r1, int r2, float side,
    bool direct, unsigned ur0, unsigned ur0r1,
    int* __restrict__ idx8, float* __restrict__ w8)
{
    const float bmin0 = -3.0f, bmin1 = -4.0f, bmin2 = -2.0f;  // BOUNDS[:,0]
    const float x = inputs[n * 3 + 0];
    const float y = inputs[n * 3 + 1];
    const float z = inputs[n * 3 + 2];
    const float p0 = (x - bmin0) / side;
    const float p1 = (y - bmin1) / side;
    const float p2 = (z - bmin2) / side;
    const float g0 = floorf(p0), g1 = floorf(p1), g2 = floorf(p2);
    const float f0 = p0 - g0, f1 = p1 - g1, f2 = p2 - g2;
    const int i0 = (int)g0, i1 = (int)g1, i2 = (int)g2;
#pragma unroll
    for (int c = 0; c < 8; ++c) {
        const int d0 = (c >> 0) & 1, d1 = (c >> 1) & 1, d2 = (c >> 2) & 1;
        const int c0 = min(max(i0 + d0, 0), r0 - 1);
        const int c1 = min(max(i1 + d1, 0), r1 - 1);
        const int c2 = min(max(i2 + d2, 0), r2 - 1);
        const unsigned u0 = (unsigned)c0, u1 = (unsigned)c1, u2 = (unsigned)c2;
        const unsigned didx = u0 + u1 * ur0 + u2 * ur0r1;
        const unsigned hidx =
            (u0 * 1u ^ u1 * 2654435761u ^ u2 * 805459861u) & (HASH_SIZE - 1u);
        idx8[c] = (int)(direct ? didx : hidx) + base;
        float ww = (d0 ? f0 : 1.0f - f0) * (d1 ? f1 : 1.0f - f1);
        ww *= (d2 ? f2 : 1.0f - f2);
        w8[c] = ww;
    }
}

// ---------------------------------------------------------------------------
// Launch 2: direct levels [0, NDIR) straight from the f32 table. 8 lanes per
// point (lane j<7 owns feats [4j,4j+4)), 4 points/thread. Level-major grid.
// ---------------------------------------------------------------------------
__global__ __launch_bounds__(256) void gather_direct_kernel(
    const float* __restrict__ inputs, const float* __restrict__ memory,
    const int* __restrict__ offsets, const int* __restrict__ res_list,
    const float* __restrict__ side_list, float* __restrict__ out, int N)
{
    const int l     = blockIdx.y;            // 0..NDIR-1
    const int chunk = blockIdx.x;            // 128-point chunk
    const int tid   = threadIdx.x;
    const int slot  = tid >> 3;              // 0..31
    const int j     = tid & 7;               // slice 0..7 (7 = pad)

    const int   base = offsets[l];
    const unsigned size = (unsigned)(offsets[l + 1] - base);
    const int r0 = res_list[l * 3 + 0];
    const int r1 = res_list[l * 3 + 1];
    const int r2 = res_list[l * 3 + 2];
    const float side = side_list[l];
    const bool direct = (((float)r0 * (float)r1) * (float)r2) <= (float)size;
    const unsigned ur0 = (unsigned)r0, ur0r1 = (unsigned)(r0 * r1);

    int nn[4];
    int idx[4][8]; float w[4][8];
#pragma unroll
    for (int p = 0; p < 4; ++p) {
        int n = chunk * 128 + p * 32 + slot;
        nn[p] = n;
        if (n >= N) n = N - 1;               // clamp loads; store masked below
        point_corners(inputs, n, base, r0, r1, r2, side, direct,
                      ur0, ur0r1, idx[p], w[p]);
    }

    if (j >= 7) return;                      // pad lane: no loads, no stores
#pragma unroll
    for (int p = 0; p < 4; ++p) {
        f32x4 acc = (f32x4)(0.0f);
#pragma unroll
        for (int c = 0; c < 8; ++c) {
            const f32x4 v =
                ((const f32x4*)(memory + (size_t)idx[p][c] * FEAT))[j];
            acc += w[p][c] * v;
        }
        if (nn[p] < N) {
            float* op = out + ((size_t)nn[p] * LVL + l) * (size_t)FEAT + j * 4;
            __builtin_nontemporal_store(acc, (f32x4*)op);
        }
    }
}

// ---------------------------------------------------------------------------
// Launch 3: hashed levels [NDIR, LVL) from packed fp16 ws (measured ~293 µs).
// 8 lanes/point, 4 points/thread -> 32 independent 8B gathers in flight.
// ---------------------------------------------------------------------------
__global__ __launch_bounds__(256) void gather_hashed_kernel(
    const float* __restrict__ inputs, const f16x4* __restrict__ wsrow,
    const int* __restrict__ offsets, const int* __restrict__ res_list,
    const float* __restrict__ side_list, float* __restrict__ out, int N)
{
    const int l     = blockIdx.y + NDIR;
    const int chunk = blockIdx.x;            // 128-point chunk
    const int tid   = threadIdx.x;
    const int slot  = tid >> 3;              // 0..31
    const int j     = tid & 7;               // slice 0..7 (7 = pad)

    const int   base = offsets[l];
    const unsigned size = (unsigned)(offsets[l + 1] - base);
    const int r0 = res_list[l * 3 + 0];
    const int r1 = res_list[l * 3 + 1];
    const int r2 = res_list[l * 3 + 2];
    const float side = side_list[l];
    const bool direct = (((float)r0 * (float)r1) * (float)r2) <= (float)size;
    const unsigned ur0 = (unsigned)r0, ur0r1 = (unsigned)(r0 * r1);

    int nn[4];
    int idx[4][8]; float w[4][8];
#pragma unroll
    for (int p = 0; p < 4; ++p) {
        int n = chunk * 128 + p * 32 + slot;
        nn[p] = n;
        if (n >= N) n = N - 1;               // clamp loads; store masked below
        point_corners(inputs, n, base, r0, r1, r2, side, direct,
                      ur0, ur0r1, idx[p], w[p]);
    }

    // Issue all 32 independent 8B gathers before any use.
    f16x4 v[4][8];
#pragma unroll
    for (int c = 0; c < 8; ++c) {
#pragma unroll
        for (int p = 0; p < 4; ++p)
            v[p][c] = wsrow[(size_t)idx[p][c] * 8 + j];
    }

#pragma unroll
    for (int p = 0; p < 4; ++p) {
        f32x4 acc = (f32x4)(0.0f);
#pragma unroll
        for (int c = 0; c < 8; ++c) {
            const float ww = w[p][c];
#pragma unroll
            for (int k = 0; k < 4; ++k) acc[k] += ww * (float)v[p][c][k];
        }
        if (j < 7 && nn[p] < N) {
            float* op = out + ((size_t)nn[p] * LVL + l) * (size_t)FEAT + j * 4;
            __builtin_nontemporal_store(acc, (f32x4*)op);
        }
    }
}

// ---------------------------------------------------------------------------
// Fallback (ws too small): all 16 levels from f32 table (R3-verified form).
// ---------------------------------------------------------------------------
__global__ __launch_bounds__(448) void hashgrid_f32_kernel(
    const float* __restrict__ inputs, const float* __restrict__ memory,
    const int* __restrict__ offsets, const int* __restrict__ res_list,
    const float* __restrict__ side_list, float* __restrict__ out, int N)
{
    const int l   = blockIdx.y;
    const int tid = threadIdx.x;
    const int pl  = tid / 7;
    const int j   = tid - pl * 7;
    const int n   = blockIdx.x * 64 + pl;
    if (n >= N) return;

    const int   base = offsets[l];
    const unsigned size = (unsigned)(offsets[l + 1] - base);
    const int r0 = res_list[l * 3 + 0];
    const int r1 = res_list[l * 3 + 1];
    const int r2 = res_list[l * 3 + 2];
    const float side = side_list[l];
    const bool direct = (((float)r0 * (float)r1) * (float)r2) <= (float)size;
    const unsigned ur0 = (unsigned)r0, ur0r1 = (unsigned)(r0 * r1);

    int idx8[8]; float w8[8];
    point_corners(inputs, n, base, r0, r1, r2, side, direct, ur0, ur0r1,
                  idx8, w8);
    f32x4 v[8];
#pragma unroll
    for (int c = 0; c < 8; ++c)
        v[c] = ((const f32x4*)(memory + (size_t)idx8[c] * FEAT))[j];
    f32x4 acc = (f32x4)(0.0f);
#pragma unroll
    for (int c = 0; c < 8; ++c) acc += w8[c] * v[c];
    f32x4* op = (f32x4*)(out + ((size_t)n * LVL + l) * (size_t)FEAT) + j;
    __builtin_nontemporal_store(acc, op);
}

extern "C" void kernel_launch(void* const* d_in, const int* in_sizes, int n_in,
                              void* d_out, int out_size, void* d_ws, size_t ws_size,
                              hipStream_t stream) {
    const float* inputs    = (const float*)d_in[0];
    const float* memory    = (const float*)d_in[1];
    const int*   offsets   = (const int*)d_in[2];
    const int*   res_list  = (const int*)d_in[3];
    const float* side_list = (const float*)d_in[4];
    float* out = (float*)d_out;

    const int N     = in_sizes[0] / 3;      // points
    const int nrows = in_sizes[1] / FEAT;   // total table rows
    const size_t ws_needed = (size_t)nrows * 64;

    if (ws_size >= ws_needed) {
        const int bpl = (N + 127) >> 7;                  // 2048 chunks/level
        // 1) pack hashed rows (upper bound on count; kernel range-checks)
        dim3 pg((nrows + 255) / 256);
        hipLaunchKernelGGL(pack_hashed_kernel, pg, dim3(256), 0, stream,
                           memory, (f16x8*)d_ws, offsets);
        // 2) direct levels from f32
        dim3 gd(bpl, NDIR);
        hipLaunchKernelGGL(gather_direct_kernel, gd, dim3(256), 0, stream,
                           inputs, memory, offsets, res_list, side_list,
                           out, N);
        // 3) hashed levels from packed ws
        dim3 gh(bpl, LVL - NDIR);
        hipLaunchKernelGGL(gather_hashed_kernel, gh, dim3(256), 0, stream,
                           inputs, (const f16x4*)d_ws, offsets, res_list,
                           side_list, out, N);
    } else {
        dim3 gb(448), gg((N + 63) / 64, LVL);
        hipLaunchKernelGGL(hashgrid_f32_kernel, gg, gb, 0, stream,
                           inputs, memory, offsets, res_list, side_list, out, N);
    }
}

// Round 11
// 679.423 us; speedup vs baseline: 1.0545x; 1.0545x over previous
//
#include <hip/hip_runtime.h>

#define FEAT 28            // features per table row
#define LVL  16            // levels
#define NDIR 6             // levels 0..5 are direct (prod(res) <= T)
#define HASH_SIZE 524288u  // T_TABLE; every hashed level has size == 2^19
#define T_TABLE  524288

typedef float    f32x4 __attribute__((ext_vector_type(4)));
typedef _Float16 f16x4 __attribute__((ext_vector_type(4)));
typedef _Float16 f16x8 __attribute__((ext_vector_type(8)));

// ---------------------------------------------------------------------------
// Pack one f32 row (28 feats) -> fp16 64B-padded row at ws + r*64B (R5-proven).
// ---------------------------------------------------------------------------
__device__ __forceinline__ void pack_row(const float* __restrict__ memory,
                                         f16x8* __restrict__ wsrow, int r)
{
    const float* src = memory + (size_t)r * FEAT;
    f16x8 o[4];
#pragma unroll
    for (int k = 0; k < 32; ++k) {
        const float v = (k < FEAT) ? src[k] : 0.0f;
        o[k >> 3][k & 7] = (_Float16)v;          // RN conversion
    }
    f16x8* dst = wsrow + (size_t)r * 4;
#pragma unroll
    for (int k = 0; k < 4; ++k) dst[k] = o[k];
}

// ---------------------------------------------------------------------------
// Corner indices + weights. EXACT reference numerics: IEEE division, floorf,
// clip, ((wx*wy)*wz) order. Hash-mod via mask is exact: a level is hashed
// iff prod(res) > T, and then its size == T == 2^19.
// ---------------------------------------------------------------------------
__device__ __forceinline__ void point_corners(
    const float* __restrict__ inputs, int n,
    int base, int r0, int r1, int r2, float side,
    bool direct, unsigned ur0, unsigned ur0r1,
    int* __restrict__ idx8, float* __restrict__ w8)
{
    const float bmin0 = -3.0f, bmin1 = -4.0f, bmin2 = -2.0f;  // BOUNDS[:,0]
    const float x = inputs[n * 3 + 0];
    const float y = inputs[n * 3 + 1];
    const float z = inputs[n * 3 + 2];
    const float p0 = (x - bmin0) / side;
    const float p1 = (y - bmin1) / side;
    const float p2 = (z - bmin2) / side;
    const float g0 = floorf(p0), g1 = floorf(p1), g2 = floorf(p2);
    const float f0 = p0 - g0, f1 = p1 - g1, f2 = p2 - g2;
    const int i0 = (int)g0, i1 = (int)g1, i2 = (int)g2;
#pragma unroll
    for (int c = 0; c < 8; ++c) {
        const int d0 = (c >> 0) & 1, d1 = (c >> 1) & 1, d2 = (c >> 2) & 1;
        const int c0 = min(max(i0 + d0, 0), r0 - 1);
        const int c1 = min(max(i1 + d1, 0), r1 - 1);
        const int c2 = min(max(i2 + d2, 0), r2 - 1);
        const unsigned u0 = (unsigned)c0, u1 = (unsigned)c1, u2 = (unsigned)c2;
        const unsigned didx = u0 + u1 * ur0 + u2 * ur0r1;
        const unsigned hidx =
            (u0 * 1u ^ u1 * 2654435761u ^ u2 * 805459861u) & (HASH_SIZE - 1u);
        idx8[c] = (int)(direct ? didx : hidx) + base;
        float ww = (d0 ? f0 : 1.0f - f0) * (d1 ? f1 : 1.0f - f1);
        ww *= (d2 ? f2 : 1.0f - f2);
        w8[c] = ww;
    }
}

// ---------------------------------------------------------------------------
// Verified gather body: one level l, one 128-point chunk, 8 lanes/point,
// 4 points/thread -> 32 independent 8B gathers from packed ws.
// ---------------------------------------------------------------------------
__device__ __forceinline__ void gather4_ws(
    const float* __restrict__ inputs, const f16x4* __restrict__ wsrow,
    const int* __restrict__ offsets, const int* __restrict__ res_list,
    const float* __restrict__ side_list, float* __restrict__ out,
    int N, int l, int chunk, int tid)
{
    const int slot = tid >> 3;               // 0..31
    const int j    = tid & 7;                // slice 0..7 (7 = pad)

    const int   base = offsets[l];
    const unsigned size = (unsigned)(offsets[l + 1] - base);
    const int r0 = res_list[l * 3 + 0];
    const int r1 = res_list[l * 3 + 1];
    const int r2 = res_list[l * 3 + 2];
    const float side = side_list[l];
    const bool direct = (((float)r0 * (float)r1) * (float)r2) <= (float)size;
    const unsigned ur0 = (unsigned)r0, ur0r1 = (unsigned)(r0 * r1);

    int nn[4];
    int idx[4][8]; float w[4][8];
#pragma unroll
    for (int p = 0; p < 4; ++p) {
        int n = chunk * 128 + p * 32 + slot;
        nn[p] = n;
        if (n >= N) n = N - 1;               // clamp loads; store masked below
        point_corners(inputs, n, base, r0, r1, r2, side, direct,
                      ur0, ur0r1, idx[p], w[p]);
    }

    // Issue all 32 independent 8B gathers before any use.
    f16x4 v[4][8];
#pragma unroll
    for (int c = 0; c < 8; ++c) {
#pragma unroll
        for (int p = 0; p < 4; ++p)
            v[p][c] = wsrow[(size_t)idx[p][c] * 8 + j];
    }

#pragma unroll
    for (int p = 0; p < 4; ++p) {
        f32x4 acc = (f32x4)(0.0f);
#pragma unroll
        for (int c = 0; c < 8; ++c) {
            const float ww = w[p][c];
#pragma unroll
            for (int k = 0; k < 4; ++k) acc[k] += ww * (float)v[p][c][k];
        }
        if (j < 7 && nn[p] < N) {
            float* op = out + ((size_t)nn[p] * LVL + l) * (size_t)FEAT + j * 4;
            __builtin_nontemporal_store(acc, (f32x4*)op);
        }
    }
}

// ---------------------------------------------------------------------------
// Launch A: pack rows [0, packSplit) = direct tables + level 6 (~35 µs).
// ---------------------------------------------------------------------------
__global__ __launch_bounds__(256) void pack_low_kernel(
    const float* __restrict__ memory, f16x8* __restrict__ wsrow, int packSplit)
{
    const int r = blockIdx.x * 256 + threadIdx.x;
    if (r < packSplit) pack_row(memory, wsrow, r);
}

// ---------------------------------------------------------------------------
// Launch B: UNIFORM-ROLE fold. Every block (1) gathers one direct-level
// chunk from ws, then (2) packs a contiguous share of rows
// [packSplit, nrows). Block turnover mixes request-bound gather with
// stream-bound pack machine-wide — no role partitioning (the R6/R7/R9 trap).
// ---------------------------------------------------------------------------
__global__ __launch_bounds__(256) void direct_gather_pack_kernel(
    const float* __restrict__ inputs, const float* __restrict__ memory,
    f16x8* __restrict__ ws_pack, const f16x4* __restrict__ wsrow,
    const int* __restrict__ offsets, const int* __restrict__ res_list,
    const float* __restrict__ side_list, float* __restrict__ out,
    int N, int packSplit, int nrows)
{
    const int tid = threadIdx.x;

    // (1) gather: level = blockIdx.y (0..NDIR-1), chunk = blockIdx.x
    gather4_ws(inputs, wsrow, offsets, res_list, side_list, out, N,
               (int)blockIdx.y, (int)blockIdx.x, tid);

    // (2) pack share of [packSplit, nrows)
    const int nb    = (int)(gridDim.x * gridDim.y);
    const int bid   = (int)(blockIdx.y * gridDim.x + blockIdx.x);
    const int total = nrows - packSplit;
    const int per   = (total + nb - 1) / nb;
    const int s     = packSplit + bid * per;
    const int e     = min(s + per, nrows);
    for (int r = s + tid; r < e; r += 256)
        pack_row(memory, ws_pack, r);
}

// ---------------------------------------------------------------------------
// Launch C: hashed levels [NDIR, LVL) from packed ws (verified ~293 µs).
// ---------------------------------------------------------------------------
__global__ __launch_bounds__(256) void gather_hashed_kernel(
    const float* __restrict__ inputs, const f16x4* __restrict__ wsrow,
    const int* __restrict__ offsets, const int* __restrict__ res_list,
    const float* __restrict__ side_list, float* __restrict__ out, int N)
{
    gather4_ws(inputs, wsrow, offsets, res_list, side_list, out, N,
               (int)blockIdx.y + NDIR, (int)blockIdx.x, (int)threadIdx.x);
}

// ---------------------------------------------------------------------------
// Fallback (ws too small): all 16 levels from f32 table (R3-verified form).
// ---------------------------------------------------------------------------
__global__ __launch_bounds__(448) void hashgrid_f32_kernel(
    const float* __restrict__ inputs, const float* __restrict__ memory,
    const int* __restrict__ offsets, const int* __restrict__ res_list,
    const float* __restrict__ side_list, float* __restrict__ out, int N)
{
    const int l   = blockIdx.y;
    const int tid = threadIdx.x;
    const int pl  = tid / 7;
    const int j   = tid - pl * 7;
    const int n   = blockIdx.x * 64 + pl;
    if (n >= N) return;

    const int   base = offsets[l];
    const unsigned size = (unsigned)(offsets[l + 1] - base);
    const int r0 = res_list[l * 3 + 0];
    const int r1 = res_list[l * 3 + 1];
    const int r2 = res_list[l * 3 + 2];
    const float side = side_list[l];
    const bool direct = (((float)r0 * (float)r1) * (float)r2) <= (float)size;
    const unsigned ur0 = (unsigned)r0, ur0r1 = (unsigned)(r0 * r1);

    int idx8[8]; float w8[8];
    point_corners(inputs, n, base, r0, r1, r2, side, direct, ur0, ur0r1,
                  idx8, w8);
    f32x4 v[8];
#pragma unroll
    for (int c = 0; c < 8; ++c)
        v[c] = ((const f32x4*)(memory + (size_t)idx8[c] * FEAT))[j];
    f32x4 acc = (f32x4)(0.0f);
#pragma unroll
    for (int c = 0; c < 8; ++c) acc += w8[c] * v[c];
    f32x4* op = (f32x4*)(out + ((size_t)n * LVL + l) * (size_t)FEAT) + j;
    __builtin_nontemporal_store(acc, op);
}

extern "C" void kernel_launch(void* const* d_in, const int* in_sizes, int n_in,
                              void* d_out, int out_size, void* d_ws, size_t ws_size,
                              hipStream_t stream) {
    const float* inputs    = (const float*)d_in[0];
    const float* memory    = (const float*)d_in[1];
    const int*   offsets   = (const int*)d_in[2];
    const int*   res_list  = (const int*)d_in[3];
    const float* side_list = (const float*)d_in[4];
    float* out = (float*)d_out;

    const int N     = in_sizes[0] / 3;      // points
    const int nrows = in_sizes[1] / FEAT;   // total table rows
    const size_t ws_needed = (size_t)nrows * 64;

    // Split: levels 6..15 are hashed with exactly T entries each, so
    // rows [0, nrows-9T) = direct tables + level 6. Even if this arithmetic
    // were off, A ∪ B still packs every row in [0, nrows) and B's gather
    // only touches rows < offsets[6] <= packSplit — safe by construction.
    const int packSplit = nrows - 9 * T_TABLE;

    if (ws_size >= ws_needed && packSplit > 0) {
        const int bpl = (N + 127) >> 7;                  // 2048 chunks/level
        // A) pack direct + level-6 rows
        dim3 ga((packSplit + 255) / 256);
        hipLaunchKernelGGL(pack_low_kernel, ga, dim3(256), 0, stream,
                           memory, (f16x8*)d_ws, packSplit);
        // B) direct gather from ws, fold-pack the remaining hashed rows
        dim3 gb(bpl, NDIR);
        hipLaunchKernelGGL(direct_gather_pack_kernel, gb, dim3(256), 0, stream,
                           inputs, memory, (f16x8*)d_ws, (const f16x4*)d_ws,
                           offsets, res_list, side_list, out, N,
                           packSplit, nrows);
        // C) hashed levels from packed ws
        dim3 gc(bpl, LVL - NDIR);
        hipLaunchKernelGGL(gather_hashed_kernel, gc, dim3(256), 0, stream,
                           inputs, (const f16x4*)d_ws, offsets, res_list,
                           side_list, out, N);
    } else {
        dim3 gbf(448), ggf((N + 63) / 64, LVL);
        hipLaunchKernelGGL(hashgrid_f32_kernel, ggf, gbf, 0, stream,
                           inputs, memory, offsets, res_list, side_list, out, N);
    }
}

// Round 12
// 660.232 us; speedup vs baseline: 1.0851x; 1.0291x over previous
//
#include <hip/hip_runtime.h>

#define FEAT 28   // features per table row
#define LVL  16   // levels
#define HASH_SIZE 524288u          // T_TABLE (power of two for all hashed levels)

typedef float    f32x4 __attribute__((ext_vector_type(4)));
typedef _Float16 f16x4 __attribute__((ext_vector_type(4)));
typedef _Float16 f16x8 __attribute__((ext_vector_type(8)));

// ---------------------------------------------------------------------------
// Pack: f32 (total,28) table -> fp16 rows padded to 64B (32 halfs), aligned.
// Row r lives at ws + r*64B; one 64B line per row. Reverse order so the low
// (first-gathered) levels are L3-hot at gather time. (R5-verified, 173 us,
// ~5.9 TB/s = stream-bound.)
// ---------------------------------------------------------------------------
__global__ __launch_bounds__(256) void pack_kernel(
    const float* __restrict__ memory, f16x8* __restrict__ wsrow, int nrows)
{
    const int g = blockIdx.x * blockDim.x + threadIdx.x;
    if (g >= nrows) return;
    const int r = nrows - 1 - g;                 // reverse order
    const float* src = memory + (size_t)r * FEAT;
    f16x8 o[4];
#pragma unroll
    for (int k = 0; k < 32; ++k) {
        const float v = (k < FEAT) ? src[k] : 0.0f;
        o[k >> 3][k & 7] = (_Float16)v;          // RN conversion
    }
    f16x8* dst = wsrow + (size_t)r * 4;
#pragma unroll
    for (int k = 0; k < 4; ++k) dst[k] = o[k];
}

// ---------------------------------------------------------------------------
// Gather: 8 lanes per point, lane j owns feats [4j,4j+4). Gather granule =
// 8B fp16 == store granule 16B f32 -> no cross-lane shuffle. 2 points per
// thread -> 16 independent 8B gathers in flight; the 8 lanes of a point
// cover exactly the row's single 64B line (1 line-request per corner).
// Level-major grid keeps each level's 33.5MB table L2/L3-warm.
// (R5-verified: 485 us, pinned at the fabric random-line service wall —
// ~69G line-requests/s chip-wide; occupancy/MLP/bytes all non-binding.)
// ---------------------------------------------------------------------------
__global__ __launch_bounds__(256) void gather_packed_kernel(
    const float* __restrict__ inputs,     // (N,3) f32
    const f16x4* __restrict__ wsrow,      // packed table, 8 x f16x4 per row
    const int*   __restrict__ offsets,    // (17) i32
    const int*   __restrict__ res_list,   // (16,3) i32
    const float* __restrict__ side_list,  // (16) f32
    float*       __restrict__ out,        // (N,16,28) f32
    int N)
{
    const int l   = blockIdx.y;
    const int tid = threadIdx.x;
    const int pl  = tid >> 3;             // local point 0..31
    const int j   = tid & 7;              // feature slice 0..7 (j==7 is pad)
    const int n0  = blockIdx.x * 64 + pl; // first point
    const int n1  = n0 + 32;              // second point
    if (n0 >= N) return;
    const int n1c = (n1 < N) ? n1 : n0;   // clamp loads; store masked below

    const int      base = offsets[l];
    const unsigned size = (unsigned)(offsets[l + 1] - base);
    const int r0 = res_list[l * 3 + 0];
    const int r1 = res_list[l * 3 + 1];
    const int r2 = res_list[l * 3 + 2];
    const float side = side_list[l];

    const float bmin0 = -3.0f, bmin1 = -4.0f, bmin2 = -2.0f;  // BOUNDS[:,0]

    const bool direct = (((float)r0 * (float)r1) * (float)r2) <= (float)size;
    const unsigned ur0   = (unsigned)r0;
    const unsigned ur0r1 = (unsigned)(r0 * r1);

    int   idx[2][8];
    float w[2][8];
#pragma unroll
    for (int p = 0; p < 2; ++p) {
        const int n = p ? n1c : n0;
        const float x = inputs[n * 3 + 0];
        const float y = inputs[n * 3 + 1];
        const float z = inputs[n * 3 + 2];
        // IEEE division: must match numpy's floor-cell choice bit-for-bit.
        const float p0 = (x - bmin0) / side;
        const float p1 = (y - bmin1) / side;
        const float p2 = (z - bmin2) / side;
        const float g0 = floorf(p0), g1 = floorf(p1), g2 = floorf(p2);
        const float f0 = p0 - g0, f1 = p1 - g1, f2 = p2 - g2;
        const int i0 = (int)g0, i1 = (int)g1, i2 = (int)g2;
#pragma unroll
        for (int c = 0; c < 8; ++c) {
            const int d0 = (c >> 0) & 1, d1 = (c >> 1) & 1, d2 = (c >> 2) & 1;
            const int c0 = min(max(i0 + d0, 0), r0 - 1);
            const int c1 = min(max(i1 + d1, 0), r1 - 1);
            const int c2 = min(max(i2 + d2, 0), r2 - 1);
            const unsigned u0 = (unsigned)c0, u1 = (unsigned)c1,
                           u2 = (unsigned)c2;
            const unsigned didx = u0 + u1 * ur0 + u2 * ur0r1;
            const unsigned hidx =
                (u0 * 1u ^ u1 * 2654435761u ^ u2 * 805459861u) &
                (HASH_SIZE - 1u);
            idx[p][c] = (int)(direct ? didx : hidx) + base;
            float ww = (d0 ? f0 : 1.0f - f0) * (d1 ? f1 : 1.0f - f1);
            ww *= (d2 ? f2 : 1.0f - f2);
            w[p][c] = ww;
        }
    }

    // Issue all 16 independent 8B gathers before any use.
    f16x4 v[2][8];
#pragma unroll
    for (int c = 0; c < 8; ++c) {
        v[0][c] = wsrow[(size_t)idx[0][c] * 8 + j];
        v[1][c] = wsrow[(size_t)idx[1][c] * 8 + j];
    }

    f32x4 acc0 = (f32x4)(0.0f), acc1 = (f32x4)(0.0f);
#pragma unroll
    for (int c = 0; c < 8; ++c) {
        const float w0 = w[0][c], w1 = w[1][c];
#pragma unroll
        for (int k = 0; k < 4; ++k) {
            acc0[k] += w0 * (float)v[0][c][k];
            acc1[k] += w1 * (float)v[1][c][k];
        }
    }

    // lane j stores feats [4j,4j+4) as one contiguous 16B f32x4 (j==7 = pad).
    if (j < 7) {
        float* op0 = out + ((size_t)n0 * LVL + l) * (size_t)FEAT + j * 4;
        __builtin_nontemporal_store(acc0, (f32x4*)op0);
        if (n1 < N) {
            float* op1 = out + ((size_t)n1 * LVL + l) * (size_t)FEAT + j * 4;
            __builtin_nontemporal_store(acc1, (f32x4*)op1);
        }
    }
}

// ---------------------------------------------------------------------------
// Fallback (ws too small): R3 kernel — 7 lanes/point, f32 table.
// ---------------------------------------------------------------------------
__global__ __launch_bounds__(448) void hashgrid_f32_kernel(
    const float* __restrict__ inputs, const float* __restrict__ memory,
    const int* __restrict__ offsets, const int* __restrict__ res_list,
    const float* __restrict__ side_list, float* __restrict__ out, int N)
{
    const int l   = blockIdx.y;
    const int tid = threadIdx.x;
    const int pl  = tid / 7;
    const int j   = tid - pl * 7;
    const int n   = blockIdx.x * 64 + pl;
    if (n >= N) return;

    const int      base = offsets[l];
    const unsigned size = (unsigned)(offsets[l + 1] - base);
    const int r0 = res_list[l * 3 + 0];
    const int r1 = res_list[l * 3 + 1];
    const int r2 = res_list[l * 3 + 2];
    const float side = side_list[l];
    const float bmin0 = -3.0f, bmin1 = -4.0f, bmin2 = -2.0f;

    const float x = inputs[n * 3 + 0];
    const float y = inputs[n * 3 + 1];
    const float z = inputs[n * 3 + 2];
    const float p0 = (x - bmin0) / side;
    const float p1 = (y - bmin1) / side;
    const float p2 = (z - bmin2) / side;
    const float g0 = floorf(p0), g1 = floorf(p1), g2 = floorf(p2);
    const float f0 = p0 - g0, f1 = p1 - g1, f2 = p2 - g2;
    const int i0 = (int)g0, i1 = (int)g1, i2 = (int)g2;

    const bool direct = (((float)r0 * (float)r1) * (float)r2) <= (float)size;
    const unsigned ur0   = (unsigned)r0;
    const unsigned ur0r1 = (unsigned)(r0 * r1);

    int idx8[8]; float w8[8];
#pragma unroll
    for (int c = 0; c < 8; ++c) {
        const int d0 = (c >> 0) & 1, d1 = (c >> 1) & 1, d2 = (c >> 2) & 1;
        const int c0 = min(max(i0 + d0, 0), r0 - 1);
        const int c1 = min(max(i1 + d1, 0), r1 - 1);
        const int c2 = min(max(i2 + d2, 0), r2 - 1);
        const unsigned u0 = (unsigned)c0, u1 = (unsigned)c1, u2 = (unsigned)c2;
        const unsigned didx = u0 + u1 * ur0 + u2 * ur0r1;
        const unsigned hidx =
            (u0 * 1u ^ u1 * 2654435761u ^ u2 * 805459861u) % size;
        idx8[c] = (int)(direct ? didx : hidx) + base;
        float w = (d0 ? f0 : 1.0f - f0) * (d1 ? f1 : 1.0f - f1);
        w *= (d2 ? f2 : 1.0f - f2);
        w8[c] = w;
    }
    f32x4 v[8];
#pragma unroll
    for (int c = 0; c < 8; ++c)
        v[c] = ((const f32x4*)(memory + (size_t)idx8[c] * FEAT))[j];
    f32x4 acc = (f32x4)(0.0f);
#pragma unroll
    for (int c = 0; c < 8; ++c) acc += w8[c] * v[c];
    f32x4* op = (f32x4*)(out + ((size_t)n * LVL + l) * (size_t)FEAT) + j;
    __builtin_nontemporal_store(acc, op);
}

extern "C" void kernel_launch(void* const* d_in, const int* in_sizes, int n_in,
                              void* d_out, int out_size, void* d_ws, size_t ws_size,
                              hipStream_t stream) {
    const float* inputs    = (const float*)d_in[0];
    const float* memory    = (const float*)d_in[1];
    const int*   offsets   = (const int*)d_in[2];
    const int*   res_list  = (const int*)d_in[3];
    const float* side_list = (const float*)d_in[4];
    float* out = (float*)d_out;

    const int N     = in_sizes[0] / 3;      // points
    const int nrows = in_sizes[1] / FEAT;   // total table rows (~5.8M)
    const size_t ws_needed = (size_t)nrows * 64;

    if (ws_size >= ws_needed) {
        dim3 pb(256), pg((nrows + 255) / 256);
        hipLaunchKernelGGL(pack_kernel, pg, pb, 0, stream,
                           memory, (f16x8*)d_ws, nrows);
        dim3 gb(256), gg((N + 63) / 64, LVL);   // x fastest -> level-major
        hipLaunchKernelGGL(gather_packed_kernel, gg, gb, 0, stream,
                           inputs, (const f16x4*)d_ws, offsets, res_list,
                           side_list, out, N);
    } else {
        dim3 gb(448), gg((N + 63) / 64, LVL);
        hipLaunchKernelGGL(hashgrid_f32_kernel, gg, gb, 0, stream,
                           inputs, memory, offsets, res_list, side_list, out, N);
    }
}